// Round 11
// baseline (167.147 us; speedup 1.0000x reference)
//
#include <hip/hip_runtime.h>
#include <hip/hip_cooperative_groups.h>

namespace cg = cooperative_groups;

// Problem constants (resolution = 512 per reference).
#define SCALE   510                // resolution - 2
#define NCELLS  (SCALE * SCALE)    // 260100
#define NF      4
#define PRIME_Y 2654435761u
#define PRIME_Z 805459861u

// Structure constants (r8/r10-proven).
#define NGRP    32       // hash groups (idx>>14)
#define NBLK    512      // grid blocks = 2 per CU (cooperative co-residency)
#define CAPA    320      // per-(block,group) segment capacity (+4.9 sigma)
#define SEGASTR 321      // +1 pad
#define NBKT    256      // bkt = u>>1 in [0,254]
#define SUBS    16       // phase-B subsets per group
#define CAPB    72
#define LROWB   258
#define NT      1024
#define SPILLCAP 65536

// Shared-memory union layout (one 47,104 B block, phases reuse it).
#define A_SEG_OFF   0        // u32[NGRP*SEGASTR] = 41,088 B
#define A_RANK_OFF  41088    // u32[NGRP]
#define A_CW_OFF    41216    // u16[NGRP]
#define B_SLICE_OFF 0        // u32[2048] = 8 KB sign-slice
#define B_SEGB_OFF  8192     // u16[CAPB*LROWB] = 37,152 B
#define B_RANK_OFF  45344    // u32[NBKT]
#define B_CA_OFF    46368    // u16[32]
#define B_WLIM_OFF  46432    // u16[NBKT]
#define H_HIST_OFF  0        // u64[2*SCALE] = 8,160 B
#define H_CL_OFF    8160     // u16[NBLK]
#define SMEM_BYTES  47104

// Workspace layout (bytes):
#define GSEGA_BYTES  ((size_t)NBLK * NGRP * CAPA * 4)      // 20,971,520
#define RECS_BYTES   ((size_t)NBLK * NBKT * CAPB * 2)      // 18,874,368
#define CNTA_BYTES   ((size_t)NGRP * NBLK * 2)             // 32,768
#define CNTG_BYTES   ((size_t)NBKT * NBLK * 2)             // 262,144
#define SIGN_BYTES   ((size_t)262144)                      // 2^19 nibbles
#define HDR_BYTES    ((size_t)256)
#define SPILLA_BYTES ((size_t)SPILLCAP * 8)
#define SPILLB_BYTES ((size_t)SPILLCAP * 4)

// ------------------------------------------------------------ signtab ------
__device__ __forceinline__ unsigned char make_signbyte(
        const float4* __restrict__ emb, unsigned int i) {
    float4 e0 = emb[2 * i + 0];
    float4 e1 = emb[2 * i + 1];
    unsigned int bb = 0;
    if (e0.x >= 0.0f) bb |= 1u << 0;
    if (e0.y >= 0.0f) bb |= 1u << 1;
    if (e0.z >= 0.0f) bb |= 1u << 2;
    if (e0.w >= 0.0f) bb |= 1u << 3;
    if (e1.x >= 0.0f) bb |= 1u << 4;
    if (e1.y >= 0.0f) bb |= 1u << 5;
    if (e1.z >= 0.0f) bb |= 1u << 6;
    if (e1.w >= 0.0f) bb |= 1u << 7;
    return (unsigned char)bb;
}

// ------------------------------------------------------------ phase A ------
// Record: (hlow14 << 18) | (u9 << 9) | v9.
__device__ __forceinline__ void split_point(
        int x, int y, int z,
        unsigned int* __restrict__ segA, unsigned int* __restrict__ rankA,
        unsigned int* __restrict__ spillcnt, unsigned long long* __restrict__ spillA,
        unsigned int hmask) {
    unsigned int h = (unsigned int)x
                   ^ ((unsigned int)y * PRIME_Y)
                   ^ ((unsigned int)z * PRIME_Z);
    unsigned int idx = h & hmask;
    unsigned int g   = idx >> 14;
    unsigned int hl  = idx & 0x3FFFu;
    unsigned int u = (unsigned int)min(max(x, 0), SCALE - 1);
    unsigned int v = (unsigned int)min(max(y, 0), SCALE - 1);
    unsigned int w = (hl << 18) | (u << 9) | v;
    unsigned int r = atomicAdd(&rankA[g], 1u);              // LDS atomic
    if (r < CAPA) {
        segA[g * SEGASTR + r] = w;                          // LDS write
    } else {
        unsigned int rs = atomicAdd(spillcnt, 1u);
        if (rs < SPILLCAP)
            spillA[rs] = ((unsigned long long)g << 32) | w;
    }
}

__device__ __forceinline__ void phaseA(
        int b, int t, char* smem,
        const int* __restrict__ inputs,
        unsigned int* __restrict__ gsegA, unsigned short* __restrict__ cntA,
        unsigned int* __restrict__ hdr, unsigned long long* __restrict__ spillA,
        int n, unsigned int hmask) {
    unsigned int*   segA  = (unsigned int*)(smem + A_SEG_OFF);
    unsigned int*   rankA = (unsigned int*)(smem + A_RANK_OFF);
    unsigned short* cwA   = (unsigned short*)(smem + A_CW_OFF);
    if (t < NGRP) rankA[t] = 0;
    __syncthreads();

    const int nquad = n >> 2;
    const int qpb = (nquad + NBLK - 1) / NBLK;
    const int q0 = b * qpb;
    const int q1 = min(q0 + qpb, nquad);
    const int4* in4 = (const int4*)inputs;
    for (int q = q0 + t; q < q1; q += NT) {
        int4 A = in4[3 * q + 0];
        int4 B = in4[3 * q + 1];
        int4 C = in4[3 * q + 2];
        split_point(A.x, A.y, A.z, segA, rankA, hdr, spillA, hmask);
        split_point(A.w, B.x, B.y, segA, rankA, hdr, spillA, hmask);
        split_point(B.z, B.w, C.x, segA, rankA, hdr, spillA, hmask);
        split_point(C.y, C.z, C.w, segA, rankA, hdr, spillA, hmask);
    }
    if (b == 0 && t == 0) {                                 // n%4 tail
        for (int p = nquad * 4; p < n; ++p)
            split_point(inputs[3 * p], inputs[3 * p + 1], inputs[3 * p + 2],
                        segA, rankA, hdr, spillA, hmask);
    }
    __syncthreads();

    if (t < NGRP) {
        unsigned int c = min(rankA[t], (unsigned int)CAPA);
        cntA[t * NBLK + b] = (unsigned short)c;
        cwA[t] = (unsigned short)min((c + 15u) & ~15u, (unsigned int)CAPA);
    }
    __syncthreads();

    for (int j = t; j < NGRP * CAPA; j += NT) {             // trimmed drain
        const int g = j / CAPA, r = j % CAPA;
        if (r < (int)cwA[g])
            gsegA[(size_t)b * NGRP * CAPA + j] = segA[g * SEGASTR + r];
    }
}

// ------------------------------------------------------------ phase B ------
__device__ __forceinline__ void proc_rec(
        unsigned int w, const unsigned int* __restrict__ slice,
        unsigned short* __restrict__ segB, unsigned int* __restrict__ rankB,
        unsigned int* __restrict__ spillcntB, unsigned int* __restrict__ spillB) {
    unsigned int hl = w >> 18;
    unsigned int u  = (w >> 9) & 0x1FFu;
    unsigned int v  = w & 0x1FFu;
    unsigned int nib = (slice[hl >> 3] >> ((hl & 7u) * 4u)) & 0xFu;
    unsigned int bkt = u >> 1;
    unsigned int rec = ((u & 1u) << 13) | (v << 4) | nib;
    unsigned int r = atomicAdd(&rankB[bkt], 1u);            // LDS atomic
    if (r < CAPB) {
        segB[r * LROWB + bkt] = (unsigned short)rec;        // LDS write
    } else {
        unsigned int rs = atomicAdd(spillcntB, 1u);
        if (rs < SPILLCAP) spillB[rs] = (bkt << 16) | rec;
    }
}

__device__ __forceinline__ void phaseB(
        int b, int t, char* smem,
        const unsigned int* __restrict__ gsegA, const unsigned short* __restrict__ cntA,
        const unsigned int* __restrict__ sig32,
        unsigned short* __restrict__ recs, unsigned short* __restrict__ cntg,
        const unsigned int* __restrict__ hdr, const unsigned long long* __restrict__ spillA,
        unsigned int* __restrict__ spillcntB, unsigned int* __restrict__ spillB) {
    unsigned int*   slice = (unsigned int*)(smem + B_SLICE_OFF);
    unsigned short* segB  = (unsigned short*)(smem + B_SEGB_OFF);
    unsigned int*   rankB = (unsigned int*)(smem + B_RANK_OFF);
    unsigned short* cA    = (unsigned short*)(smem + B_CA_OFF);
    unsigned short* wlim  = (unsigned short*)(smem + B_WLIM_OFF);
    const int g = b / SUBS, k = b % SUBS;
    if (t < NBKT) rankB[t] = 0;
    if (t < 32)  cA[t] = cntA[g * NBLK + k * 32 + t];
    for (int i = t; i < 2048; i += NT) slice[i] = sig32[g * 2048 + i];
    __syncthreads();

    for (int j = t; j < 32 * CAPA; j += NT) {
        const int s = j / CAPA, r = j % CAPA;
        if (r < (int)cA[s]) {
            unsigned int w = gsegA[((size_t)(k * 32 + s) * NGRP + g) * CAPA + r];
            proc_rec(w, slice, segB, rankB, spillcntB, spillB);
        }
    }
    if (k == 0) {                                           // group's A-spills
        unsigned int ns = min(hdr[0], (unsigned int)SPILLCAP);
        for (unsigned int i2 = t; i2 < ns; i2 += NT) {
            unsigned long long e = spillA[i2];
            if ((unsigned int)(e >> 32) == (unsigned int)g)
                proc_rec((unsigned int)e, slice, segB, rankB, spillcntB, spillB);
        }
    }
    __syncthreads();

    if (t < NBKT) {
        unsigned int c = min(rankB[t], (unsigned int)CAPB);
        cntg[t * NBLK + b] = (unsigned short)c;
        wlim[t] = (unsigned short)min(((c + 31u) >> 5) << 4,
                                      (unsigned int)(CAPB / 2));
    }
    __syncthreads();

    unsigned int* gout = (unsigned int*)(recs + (size_t)b * NBKT * CAPB);
    for (int j = t; j < NBKT * CAPB / 2; j += NT) {         // trimmed drain
        const int bkt = j / (CAPB / 2);
        const int wi  = j % (CAPB / 2);
        if (wi < (int)wlim[bkt]) {
            const int r = wi * 2;
            unsigned int lo = segB[r * LROWB + bkt];
            unsigned int hi = segB[(r + 1) * LROWB + bkt];
            gout[j] = lo | (hi << 16);
        }
    }
}

// ------------------------------------------------------------ phase H ------
__device__ __forceinline__ void hist_add(unsigned long long* hist,
                                         unsigned int rec) {
    unsigned int nib = rec & 0xFu;
    unsigned int v   = (rec >> 4) & 0x1FFu;
    unsigned int ul  = rec >> 13;
    unsigned long long add = 1ull
        | ((unsigned long long)(nib & 1u)        << 12)
        | ((unsigned long long)((nib >> 1) & 1u) << 24)
        | ((unsigned long long)((nib >> 2) & 1u) << 36)
        | ((unsigned long long)((nib >> 3) & 1u) << 48);
    atomicAdd(&hist[ul * SCALE + v], add);
}

__device__ __forceinline__ void phaseH(
        int b, int t, char* smem,
        const unsigned short* __restrict__ recs, const unsigned short* __restrict__ cntg,
        const unsigned int* __restrict__ hdr, const unsigned int* __restrict__ spillB,
        float* __restrict__ out) {
    unsigned long long* hist = (unsigned long long*)(smem + H_HIST_OFF);
    unsigned short*     cl   = (unsigned short*)(smem + H_CL_OFF);
    for (int i = t; i < 2 * SCALE; i += NT) hist[i] = 0;
    if (t < NBLK) cl[t] = cntg[b * NBLK + t];
    __syncthreads();

    for (int j = t; j < NBLK * CAPB / 2; j += NT) {
        const int s  = j / (CAPB / 2);
        const int wi = j % (CAPB / 2);
        const int c  = cl[s];
        const int wl = min(((c + 31) >> 5) << 4, CAPB / 2);
        if (wi < wl) {
            const unsigned int* segp = (const unsigned int*)
                (recs + ((size_t)s * NBKT + b) * CAPB);
            unsigned int w = segp[wi];
            const int r0 = wi * 2;
            if (r0 < c)     hist_add(hist, w & 0xFFFFu);
            if (r0 + 1 < c) hist_add(hist, w >> 16);
        }
    }
    const unsigned int ns = min(hdr[1], (unsigned int)SPILLCAP);
    for (unsigned int i2 = t; i2 < ns; i2 += NT) {
        unsigned int w = spillB[i2];
        if ((int)(w >> 16) == b) hist_add(hist, w & 0xFFFFu);
    }
    __syncthreads();

    const size_t outbase = (size_t)(2 * b) * SCALE * 8;     // floats
    for (int c = t; c < 2 * SCALE; c += NT) {
        unsigned long long vv = hist[c];
        float cc = (float)(unsigned int)(vv & 0xFFFull);
        float p0 = (float)(unsigned int)((vv >> 12) & 0xFFFull);
        float p1 = (float)(unsigned int)((vv >> 24) & 0xFFFull);
        float p2 = (float)(unsigned int)((vv >> 36) & 0xFFFull);
        float p3 = (float)(unsigned int)((vv >> 48) & 0xFFFull);
        float inv = 1.0f / (cc + 1e-6f);
        float4 o0, o1;
        o0.x = p0 * inv; o0.y = (cc - p0) * inv;
        o0.z = p1 * inv; o0.w = (cc - p1) * inv;
        o1.x = p2 * inv; o1.y = (cc - p2) * inv;
        o1.z = p3 * inv; o1.w = (cc - p3) * inv;
        float4* op = (float4*)(out + outbase + (size_t)c * 8);
        op[0] = o0;
        op[1] = o1;
    }
}

// --------------------------------------------------------- mega kernel -----
__global__ __launch_bounds__(NT, 8)   // 8 waves/EU -> 2 blocks/CU guaranteed
void mega_kernel(const int* __restrict__ inputs, const float4* __restrict__ emb,
                 unsigned int* __restrict__ gsegA, unsigned short* __restrict__ cntA,
                 unsigned char* __restrict__ signtab, unsigned int* __restrict__ hdr,
                 unsigned long long* __restrict__ spillA, unsigned int* __restrict__ spillB,
                 unsigned short* __restrict__ recs, unsigned short* __restrict__ cntg,
                 float* __restrict__ out, int n, unsigned int hmask) {
    __shared__ __align__(16) char smem[SMEM_BYTES];
    const int t = threadIdx.x, b = blockIdx.x;

    phaseA(b, t, smem, inputs, gsegA, cntA, hdr, spillA, n, hmask);
    // Distributed signtab build: 512 B per block, overlaps A stragglers.
    if (t < 512) {
        unsigned int i = (unsigned int)b * 512u + (unsigned int)t;
        signtab[i] = make_signbyte(emb, i);
    }
    cg::this_grid().sync();

    phaseB(b, t, smem, gsegA, cntA, (const unsigned int*)signtab,
           recs, cntg, hdr, spillA, hdr + 1, spillB);
    cg::this_grid().sync();

    if (b < 255)
        phaseH(b, t, smem, recs, cntg, hdr, spillB, out);
}

// ---------------------------------- non-cooperative fallback wrappers ------
__global__ __launch_bounds__(NT)
void signtab_kernel(const float4* __restrict__ emb,
                    unsigned char* __restrict__ signtab) {
    unsigned int i = blockIdx.x * NT + threadIdx.x;         // 256 blocks
    signtab[i] = make_signbyte(emb, i);
}

__global__ __launch_bounds__(NT)
void phaseA_kernel(const int* __restrict__ inputs,
                   unsigned int* __restrict__ gsegA, unsigned short* __restrict__ cntA,
                   unsigned int* __restrict__ hdr, unsigned long long* __restrict__ spillA,
                   int n, unsigned int hmask) {
    __shared__ __align__(16) char smem[SMEM_BYTES];
    phaseA(blockIdx.x, threadIdx.x, smem, inputs, gsegA, cntA, hdr, spillA, n, hmask);
}

__global__ __launch_bounds__(NT)
void phaseB_kernel(const unsigned int* __restrict__ gsegA,
                   const unsigned short* __restrict__ cntA,
                   const unsigned int* __restrict__ sig32,
                   unsigned short* __restrict__ recs, unsigned short* __restrict__ cntg,
                   unsigned int* __restrict__ hdr,
                   const unsigned long long* __restrict__ spillA,
                   unsigned int* __restrict__ spillB) {
    __shared__ __align__(16) char smem[SMEM_BYTES];
    phaseB(blockIdx.x, threadIdx.x, smem, gsegA, cntA, sig32, recs, cntg,
           hdr, spillA, hdr + 1, spillB);
}

__global__ __launch_bounds__(NT)
void phaseH_kernel(const unsigned short* __restrict__ recs,
                   const unsigned short* __restrict__ cntg,
                   const unsigned int* __restrict__ hdr,
                   const unsigned int* __restrict__ spillB,
                   float* __restrict__ out) {
    __shared__ __align__(16) char smem[SMEM_BYTES];
    phaseH(blockIdx.x, threadIdx.x, smem, recs, cntg, hdr, spillB, out);
}

// --------------------------------------------------- fallback (tiny ws) ----
__global__ void scatter_fb_kernel(const int* __restrict__ inputs,
                                  const float4* __restrict__ emb,
                                  unsigned long long* __restrict__ cnt,
                                  int n, unsigned int hmask) {
    int i = blockIdx.x * blockDim.x + threadIdx.x;
    if (i >= n) return;
    int x = inputs[3 * i], y = inputs[3 * i + 1], z = inputs[3 * i + 2];
    unsigned int h = (unsigned int)x ^ ((unsigned int)y * PRIME_Y)
                   ^ ((unsigned int)z * PRIME_Z);
    float4 e = emb[h & hmask];
    unsigned long long add = 1ull;
    if (e.x >= 0.0f) add |= 1ull << 12;
    if (e.y >= 0.0f) add |= 1ull << 24;
    if (e.z >= 0.0f) add |= 1ull << 36;
    if (e.w >= 0.0f) add |= 1ull << 48;
    int u = min(max(x, 0), SCALE - 1);
    int v = min(max(y, 0), SCALE - 1);
    atomicAdd(&cnt[u * SCALE + v], add);
}

__global__ void normalize_fb_kernel(const unsigned long long* __restrict__ cnt,
                                    float* __restrict__ out) {
    int i = blockIdx.x * blockDim.x + threadIdx.x;
    if (i >= NCELLS) return;
    unsigned long long v = cnt[i];
    float c  = (float)(unsigned int)(v & 0xFFFull);
    float p0 = (float)(unsigned int)((v >> 12) & 0xFFFull);
    float p1 = (float)(unsigned int)((v >> 24) & 0xFFFull);
    float p2 = (float)(unsigned int)((v >> 36) & 0xFFFull);
    float p3 = (float)(unsigned int)((v >> 48) & 0xFFFull);
    float inv = 1.0f / (c + 1e-6f);
    float4 o0, o1;
    o0.x = p0 * inv; o0.y = (c - p0) * inv;
    o0.z = p1 * inv; o0.w = (c - p1) * inv;
    o1.x = p2 * inv; o1.y = (c - p2) * inv;
    o1.z = p3 * inv; o1.w = (c - p3) * inv;
    float4* outv = (float4*)(out + (size_t)i * 8);
    outv[0] = o0; outv[1] = o1;
}

// ------------------------------------------------------------------ launch --
extern "C" void kernel_launch(void* const* d_in, const int* in_sizes, int n_in,
                              void* d_out, int out_size, void* d_ws, size_t ws_size,
                              hipStream_t stream) {
    const int*    inputs = (const int*)d_in[0];
    const float4* emb    = (const float4*)d_in[1];
    int n = in_sizes[0] / 3;
    unsigned int hsize = (unsigned int)(in_sizes[1] / NF);
    unsigned int hmask = hsize - 1;
    float* outp = (float*)d_out;

    const size_t need = GSEGA_BYTES + RECS_BYTES + CNTA_BYTES + CNTG_BYTES
                      + SIGN_BYTES + HDR_BYTES + SPILLA_BYTES + SPILLB_BYTES;

    if (ws_size >= need && hsize == (1u << 19)) {
        char* w = (char*)d_ws;
        unsigned int*       gsegA   = (unsigned int*)w;            w += GSEGA_BYTES;
        unsigned short*     recs    = (unsigned short*)w;          w += RECS_BYTES;
        unsigned short*     cntA    = (unsigned short*)w;          w += CNTA_BYTES;
        unsigned short*     cntg    = (unsigned short*)w;          w += CNTG_BYTES;
        unsigned char*      signtab = (unsigned char*)w;           w += SIGN_BYTES;
        unsigned int*       hdr     = (unsigned int*)w;            w += HDR_BYTES;
        unsigned long long* spillA  = (unsigned long long*)w;      w += SPILLA_BYTES;
        unsigned int*       spillB  = (unsigned int*)w;

        hipMemsetAsync(hdr, 0, 8, stream);                  // spill counters

        int dev = 0, coop = 0;
        hipGetDevice(&dev);
        hipDeviceGetAttribute(&coop, hipDeviceAttributeCooperativeLaunch, dev);
        if (coop) {
            void* kargs[] = {
                (void*)&inputs, (void*)&emb, (void*)&gsegA, (void*)&cntA,
                (void*)&signtab, (void*)&hdr, (void*)&spillA, (void*)&spillB,
                (void*)&recs, (void*)&cntg, (void*)&outp, (void*)&n, (void*)&hmask };
            hipLaunchCooperativeKernel((void*)mega_kernel, dim3(NBLK), dim3(NT),
                                       kargs, 0, stream);
        } else {
            signtab_kernel<<<256, NT, 0, stream>>>(emb, signtab);
            phaseA_kernel<<<NBLK, NT, 0, stream>>>(inputs, gsegA, cntA, hdr,
                                                   spillA, n, hmask);
            phaseB_kernel<<<NBLK, NT, 0, stream>>>(gsegA, cntA,
                (const unsigned int*)signtab, recs, cntg, hdr, spillA, spillB);
            phaseH_kernel<<<255, NT, 0, stream>>>(recs, cntg, hdr, spillB, outp);
        }
    } else {
        unsigned long long* cnt = (unsigned long long*)d_ws;
        hipMemsetAsync(cnt, 0, (size_t)NCELLS * 8, stream);
        const int threads = 256;
        scatter_fb_kernel<<<(n + threads - 1) / threads, threads, 0, stream>>>(
            inputs, emb, cnt, n, hmask);
        normalize_fb_kernel<<<(NCELLS + threads - 1) / threads, threads, 0, stream>>>(
            cnt, outp);
    }
}

// Round 12
// 44.754 us; speedup vs baseline: 3.7348x; 3.7348x over previous
//
#include <hip/hip_runtime.h>

// Problem constants (resolution = 512 per reference).
#define SCALE   510                // resolution - 2
#define NCELLS  (SCALE * SCALE)    // 260100
#define NF      4
#define PRIME_Y 2654435761u
#define PRIME_Z 805459861u

// Phase A: hash-partition into 32 groups (idx>>14), LDS-staged.
#define NGRP    32
#define NBLKA   512
#define CAPA    320      // per-(block,group) mean 244, +4.9 sigma
#define PAT     1024
#define SEGASTR 321      // +1 pad: bank = (g+r)%32, random g spreads

// Phase B: per-group table slice in LDS + x-bucket binning (r6 format).
#define NBKT    256      // bkt = u>>1 in [0,254]
#define NBLKB   512      // 32 groups x 16 subsets
#define SUBS    16
#define CAPB    72       // mean 30.5 (61 for bkt 254); spill path covers tails
#define PBT     1024
#define LROWB   258      // u16 stride: drain conflict-free, bin spread by bkt

#define PHT     1024
#define SPILLCAP 65536

// Workspace layout (bytes, all 256-aligned by construction):
#define GSEGA_BYTES  ((size_t)NBLKA * NGRP * CAPA * 4)     // 20,971,520
#define RECS_BYTES   ((size_t)NBLKB * NBKT * CAPB * 2)     // 18,874,368
#define CNTA_BYTES   ((size_t)NGRP * NBLKA * 2)            // 32,768
#define CNTG_BYTES   ((size_t)NBKT * NBLKB * 2)            // 262,144
#define SIGN_BYTES   ((size_t)262144)                      // 2^19 nibbles
#define HDR_BYTES    ((size_t)256)
#define SPILLA_BYTES ((size_t)SPILLCAP * 8)
#define SPILLB_BYTES ((size_t)SPILLCAP * 4)

// ---------------------------------------------------------------- signtab ---
// Pack 4 sign bits per hash entry into a nibble (2^19 entries -> 256 KB).
// Also zeroes the two spill counters.
__global__ void signtab_kernel(const float4* __restrict__ emb,
                               unsigned char* __restrict__ signtab,
                               unsigned int* __restrict__ hdr,
                               unsigned int hsize) {
    unsigned int i = blockIdx.x * blockDim.x + threadIdx.x;   // byte index
    if (i < 2) hdr[i] = 0;
    if (i * 2 >= hsize) return;
    float4 e0 = emb[2 * i + 0];
    float4 e1 = emb[2 * i + 1];
    unsigned int b = 0;
    if (e0.x >= 0.0f) b |= 1u << 0;
    if (e0.y >= 0.0f) b |= 1u << 1;
    if (e0.z >= 0.0f) b |= 1u << 2;
    if (e0.w >= 0.0f) b |= 1u << 3;
    if (e1.x >= 0.0f) b |= 1u << 4;
    if (e1.y >= 0.0f) b |= 1u << 5;
    if (e1.z >= 0.0f) b |= 1u << 6;
    if (e1.w >= 0.0f) b |= 1u << 7;
    signtab[i] = (unsigned char)b;
}

// -------------------------------------------------------- phase A: split ----
// Record: (hlow14 << 18) | (u9 << 9) | v9  — exactly 32 bits.
__device__ __forceinline__ void split_point(
        int x, int y, int z,
        unsigned int* __restrict__ segA, unsigned int* __restrict__ rankA,
        unsigned int* __restrict__ spillcnt, unsigned long long* __restrict__ spillA,
        unsigned int hmask) {
    unsigned int h = (unsigned int)x
                   ^ ((unsigned int)y * PRIME_Y)
                   ^ ((unsigned int)z * PRIME_Z);
    unsigned int idx = h & hmask;
    unsigned int g   = idx >> 14;          // 5 bits (hsize == 2^19 guarded)
    unsigned int hl  = idx & 0x3FFFu;      // 14 bits
    unsigned int u = (unsigned int)min(max(x, 0), SCALE - 1);
    unsigned int v = (unsigned int)min(max(y, 0), SCALE - 1);
    unsigned int w = (hl << 18) | (u << 9) | v;
    unsigned int r = atomicAdd(&rankA[g], 1u);              // LDS atomic
    if (r < CAPA) {
        segA[g * SEGASTR + r] = w;                          // LDS write
    } else {                                                // ~0 expected
        unsigned int rs = atomicAdd(spillcnt, 1u);
        if (rs < SPILLCAP)
            spillA[rs] = ((unsigned long long)g << 32) | w;
    }
}

__global__ __launch_bounds__(PAT)
void hashsplit_kernel(const int* __restrict__ inputs,
                      unsigned int* __restrict__ gsegA,
                      unsigned short* __restrict__ cntA,
                      unsigned int* __restrict__ hdr,
                      unsigned long long* __restrict__ spillA,
                      int n, unsigned int hmask) {
    __shared__ unsigned int segA[NGRP * SEGASTR];           // 41,088 B
    __shared__ unsigned int rankA[NGRP];
    const int t = threadIdx.x, b = blockIdx.x;
    if (t < NGRP) rankA[t] = 0;
    __syncthreads();

    const int nquad = n >> 2;
    const int qpb = (nquad + NBLKA - 1) / NBLKA;
    const int q0 = b * qpb;
    const int q1 = min(q0 + qpb, nquad);
    const int4* in4 = (const int4*)inputs;
    for (int q = q0 + t; q < q1; q += PAT) {
        int4 A = in4[3 * q + 0];
        int4 B = in4[3 * q + 1];
        int4 C = in4[3 * q + 2];
        split_point(A.x, A.y, A.z, segA, rankA, hdr, spillA, hmask);
        split_point(A.w, B.x, B.y, segA, rankA, hdr, spillA, hmask);
        split_point(B.z, B.w, C.x, segA, rankA, hdr, spillA, hmask);
        split_point(C.y, C.z, C.w, segA, rankA, hdr, spillA, hmask);
    }
    if (b == 0 && t == 0) {                                 // n%4 tail
        for (int p = nquad * 4; p < n; ++p)
            split_point(inputs[3 * p], inputs[3 * p + 1], inputs[3 * p + 2],
                        segA, rankA, hdr, spillA, hmask);
    }
    __syncthreads();

    // Coalesced drain: [g][r] -> gsegA[b][g][r].
    for (int j = t; j < NGRP * CAPA; j += PAT)
        gsegA[(size_t)b * NGRP * CAPA + j] =
            segA[(j / CAPA) * SEGASTR + (j % CAPA)];
    if (t < NGRP)
        cntA[t * NBLKA + b] = (unsigned short)min(rankA[t], (unsigned int)CAPA);
}

// ------------------------------------------------------ phase B: lookup -----
// Output record: bits[0,4)=nib, bits[4,13)=v, bit13 = u&1; bucket = u>>1.
__device__ __forceinline__ void proc_rec(
        unsigned int w,
        const unsigned int* __restrict__ slice,
        unsigned short* __restrict__ segB, unsigned int* __restrict__ rankB,
        unsigned int* __restrict__ spillcntB, unsigned int* __restrict__ spillB) {
    unsigned int hl = w >> 18;
    unsigned int u  = (w >> 9) & 0x1FFu;
    unsigned int v  = w & 0x1FFu;
    unsigned int nib = (slice[hl >> 3] >> ((hl & 7u) * 4u)) & 0xFu;
    unsigned int bkt = u >> 1;
    unsigned int rec = ((u & 1u) << 13) | (v << 4) | nib;
    unsigned int r = atomicAdd(&rankB[bkt], 1u);            // LDS atomic
    if (r < CAPB) {
        segB[r * LROWB + bkt] = (unsigned short)rec;        // LDS write
    } else {
        unsigned int rs = atomicAdd(spillcntB, 1u);
        if (rs < SPILLCAP) spillB[rs] = (bkt << 16) | rec;
    }
}

__global__ __launch_bounds__(PBT)
void binlookup_kernel(const unsigned int* __restrict__ gsegA,
                      const unsigned short* __restrict__ cntA,
                      const unsigned int* __restrict__ sig32,
                      unsigned short* __restrict__ recs,
                      unsigned short* __restrict__ cntg,
                      const unsigned int* __restrict__ hdr,   // [0]=nspillA
                      const unsigned long long* __restrict__ spillA,
                      unsigned int* __restrict__ spillcntB,   // = hdr+1
                      unsigned int* __restrict__ spillB) {
    __shared__ unsigned int   slice[2048];                  // 8 KB sign-slice
    __shared__ unsigned short segB[CAPB * LROWB];           // 37,152 B
    __shared__ unsigned int   rankB[NBKT];                  // 1 KB
    __shared__ unsigned short cA[32];
    const int t = threadIdx.x, b = blockIdx.x;
    const int g = b / SUBS, k = b % SUBS;
    if (t < NBKT) rankB[t] = 0;
    if (t < 32)  cA[t] = cntA[g * NBLKA + k * 32 + t];
    for (int i = t; i < 2048; i += PBT) slice[i] = sig32[g * 2048 + i];
    __syncthreads();

    // 32 source segments x CAPA records, coalesced reads.
    for (int j = t; j < 32 * CAPA; j += PBT) {
        const int s = j / CAPA, r = j % CAPA;
        if (r < (int)cA[s]) {
            unsigned int w = gsegA[((size_t)(k * 32 + s) * NGRP + g) * CAPA + r];
            proc_rec(w, slice, segB, rankB, spillcntB, spillB);
        }
    }
    if (k == 0) {                                           // group's A-spills
        unsigned int ns = min(hdr[0], (unsigned int)SPILLCAP);
        for (unsigned int i2 = t; i2 < ns; i2 += PBT) {
            unsigned long long e = spillA[i2];
            if ((unsigned int)(e >> 32) == (unsigned int)g)
                proc_rec((unsigned int)e, slice, segB, rankB, spillcntB, spillB);
        }
    }
    __syncthreads();

    // Coalesced drain in histnorm's format: recs[b][bkt][CAPB] u16 (u32 pairs).
    unsigned int* gout = (unsigned int*)(recs + (size_t)b * NBKT * CAPB);
    for (int j = t; j < NBKT * CAPB / 2; j += PBT) {
        const int bkt = j / (CAPB / 2);
        const int r   = (j % (CAPB / 2)) * 2;
        unsigned int lo = segB[r * LROWB + bkt];
        unsigned int hi = segB[(r + 1) * LROWB + bkt];
        gout[j] = lo | (hi << 16);
    }
    if (t < NBKT)
        cntg[t * NBLKB + b] = (unsigned short)min(rankB[t], (unsigned int)CAPB);
}

// --------------------------------------------------------------- histnorm ---
__device__ __forceinline__ void hist_add(unsigned long long* hist,
                                         unsigned int rec) {
    unsigned int nib = rec & 0xFu;
    unsigned int v   = (rec >> 4) & 0x1FFu;
    unsigned int ul  = rec >> 13;
    unsigned long long add = 1ull
        | ((unsigned long long)(nib & 1u)        << 12)
        | ((unsigned long long)((nib >> 1) & 1u) << 24)
        | ((unsigned long long)((nib >> 2) & 1u) << 36)
        | ((unsigned long long)((nib >> 3) & 1u) << 48);
    atomicAdd(&hist[ul * SCALE + v], add);
}

// 255 blocks: block b handles bucket b -> grid rows {2b, 2b+1}.
__global__ __launch_bounds__(PHT)
void histnorm_kernel(const unsigned short* __restrict__ recs,
                     const unsigned short* __restrict__ cntg,
                     const unsigned int* __restrict__ hdr,   // [1]=nspillB
                     const unsigned int* __restrict__ spillB,
                     float* __restrict__ out) {
    __shared__ unsigned long long hist[2 * SCALE];           // 8.2 KB
    __shared__ unsigned short cl[NBLKB];
    const int t = threadIdx.x, b = blockIdx.x;               // b in [0,255)
    for (int i = t; i < 2 * SCALE; i += PHT) hist[i] = 0;
    if (t < NBLKB) cl[t] = cntg[b * NBLKB + t];
    __syncthreads();

    for (int j = t; j < NBLKB * CAPB / 2; j += PHT) {
        const int s  = j / (CAPB / 2);
        const int wi = j % (CAPB / 2);
        const unsigned int* segp = (const unsigned int*)
            (recs + ((size_t)s * NBKT + b) * CAPB);
        unsigned int w = segp[wi];
        const int c = cl[s], r0 = wi * 2;
        if (r0 < c)     hist_add(hist, w & 0xFFFFu);
        if (r0 + 1 < c) hist_add(hist, w >> 16);
    }
    const unsigned int ns = min(hdr[1], (unsigned int)SPILLCAP);
    for (unsigned int i2 = t; i2 < ns; i2 += PHT) {
        unsigned int w = spillB[i2];
        if ((int)(w >> 16) == b) hist_add(hist, w & 0xFFFFu);
    }
    __syncthreads();

    const size_t outbase = (size_t)(2 * b) * SCALE * 8;     // floats
    for (int c = t; c < 2 * SCALE; c += PHT) {
        unsigned long long vv = hist[c];
        float cc = (float)(unsigned int)(vv & 0xFFFull);
        float p0 = (float)(unsigned int)((vv >> 12) & 0xFFFull);
        float p1 = (float)(unsigned int)((vv >> 24) & 0xFFFull);
        float p2 = (float)(unsigned int)((vv >> 36) & 0xFFFull);
        float p3 = (float)(unsigned int)((vv >> 48) & 0xFFFull);
        float inv = 1.0f / (cc + 1e-6f);
        float4 o0, o1;
        o0.x = p0 * inv; o0.y = (cc - p0) * inv;
        o0.z = p1 * inv; o0.w = (cc - p1) * inv;
        o1.x = p2 * inv; o1.y = (cc - p2) * inv;
        o1.z = p3 * inv; o1.w = (cc - p3) * inv;
        float4* op = (float4*)(out + outbase + (size_t)c * 8);
        op[0] = o0;
        op[1] = o1;
    }
}

// --------------------------------------------------- fallback (tiny ws) -----
__global__ void scatter_fb_kernel(const int* __restrict__ inputs,
                                  const float4* __restrict__ emb,
                                  unsigned long long* __restrict__ cnt,
                                  int n, unsigned int hmask) {
    int i = blockIdx.x * blockDim.x + threadIdx.x;
    if (i >= n) return;
    int x = inputs[3 * i], y = inputs[3 * i + 1], z = inputs[3 * i + 2];
    unsigned int h = (unsigned int)x ^ ((unsigned int)y * PRIME_Y)
                   ^ ((unsigned int)z * PRIME_Z);
    float4 e = emb[h & hmask];
    unsigned long long add = 1ull;
    if (e.x >= 0.0f) add |= 1ull << 12;
    if (e.y >= 0.0f) add |= 1ull << 24;
    if (e.z >= 0.0f) add |= 1ull << 36;
    if (e.w >= 0.0f) add |= 1ull << 48;
    int u = min(max(x, 0), SCALE - 1);
    int v = min(max(y, 0), SCALE - 1);
    atomicAdd(&cnt[u * SCALE + v], add);
}

__global__ void normalize_fb_kernel(const unsigned long long* __restrict__ cnt,
                                    float* __restrict__ out) {
    int i = blockIdx.x * blockDim.x + threadIdx.x;
    if (i >= NCELLS) return;
    unsigned long long v = cnt[i];
    float c  = (float)(unsigned int)(v & 0xFFFull);
    float p0 = (float)(unsigned int)((v >> 12) & 0xFFFull);
    float p1 = (float)(unsigned int)((v >> 24) & 0xFFFull);
    float p2 = (float)(unsigned int)((v >> 36) & 0xFFFull);
    float p3 = (float)(unsigned int)((v >> 48) & 0xFFFull);
    float inv = 1.0f / (c + 1e-6f);
    float4 o0, o1;
    o0.x = p0 * inv; o0.y = (c - p0) * inv;
    o0.z = p1 * inv; o0.w = (c - p1) * inv;
    o1.x = p2 * inv; o1.y = (c - p2) * inv;
    o1.z = p3 * inv; o1.w = (c - p3) * inv;
    float4* outv = (float4*)(out + (size_t)i * 8);
    outv[0] = o0; outv[1] = o1;
}

// ------------------------------------------------------------------ launch --
extern "C" void kernel_launch(void* const* d_in, const int* in_sizes, int n_in,
                              void* d_out, int out_size, void* d_ws, size_t ws_size,
                              hipStream_t stream) {
    const int*    inputs = (const int*)d_in[0];
    const float4* emb    = (const float4*)d_in[1];
    int n = in_sizes[0] / 3;
    unsigned int hsize = (unsigned int)(in_sizes[1] / NF);
    unsigned int hmask = hsize - 1;

    const size_t need = GSEGA_BYTES + RECS_BYTES + CNTA_BYTES + CNTG_BYTES
                      + SIGN_BYTES + HDR_BYTES + SPILLA_BYTES + SPILLB_BYTES;

    if (ws_size >= need && hsize == (1u << 19)) {
        char* w = (char*)d_ws;
        unsigned int*       gsegA   = (unsigned int*)w;            w += GSEGA_BYTES;
        unsigned short*     recs    = (unsigned short*)w;          w += RECS_BYTES;
        unsigned short*     cntA    = (unsigned short*)w;          w += CNTA_BYTES;
        unsigned short*     cntg    = (unsigned short*)w;          w += CNTG_BYTES;
        unsigned char*      signtab = (unsigned char*)w;           w += SIGN_BYTES;
        unsigned int*       hdr     = (unsigned int*)w;            w += HDR_BYTES;
        unsigned long long* spillA  = (unsigned long long*)w;      w += SPILLA_BYTES;
        unsigned int*       spillB  = (unsigned int*)w;

        signtab_kernel<<<((int)(hsize / 2) + 255) / 256, 256, 0, stream>>>(
            emb, signtab, hdr, hsize);
        hashsplit_kernel<<<NBLKA, PAT, 0, stream>>>(
            inputs, gsegA, cntA, hdr, spillA, n, hmask);
        binlookup_kernel<<<NBLKB, PBT, 0, stream>>>(
            gsegA, cntA, (const unsigned int*)signtab, recs, cntg,
            hdr, spillA, hdr + 1, spillB);
        histnorm_kernel<<<255, PHT, 0, stream>>>(
            recs, cntg, hdr, spillB, (float*)d_out);
    } else {
        unsigned long long* cnt = (unsigned long long*)d_ws;
        hipMemsetAsync(cnt, 0, (size_t)NCELLS * 8, stream);
        const int threads = 256;
        scatter_fb_kernel<<<(n + threads - 1) / threads, threads, 0, stream>>>(
            inputs, emb, cnt, n, hmask);
        normalize_fb_kernel<<<(NCELLS + threads - 1) / threads, threads, 0, stream>>>(
            cnt, (float*)d_out);
    }
}